// Round 14
// baseline (3257.715 us; speedup 1.0000x reference)
//
#include <hip/hip_runtime.h>
#include <cmath>

// ---------------------------------------------------------------------------
// RPN head on MI355X. fp32 throughout; conv FMA chain order (ic,ky,kx asc,
// fmaf(w,x,acc)) and the head's 16x16 two-level reduction are bit-exact vs
// the np reference (absmax 0.0 through R19) — preserve both exactly.
//
// R20 = R19 (conv + topk<false> frozen) + {nms_scan, topk<true>} fused.
// Conv (2672us, 49% of fp32 peak, VALU 78.6%) is a fully mapped structural
// plateau: occupancy wall (132-reg acc tile -> 3 waves/SIMD; R7/R10 caps
// spill), tile optimum 8x8 (R14), ILP-via-regs loses occupancy (R9/R13/
// R16), barriers amortized to the LDS limit (R19; 3-ic chunks would drop
// to 2 blk/CU). DO NOT PERTURB conv or topk<false> (R17 tail best; R18's
// two-phase split regressed and was reverted).
// R20 new: final kernel nms_topk_final = per-image block (1024 thr):
// waves 0-4 run the 5 per-level nms_scan bodies (verbatim wave-shuffle
// code), write masked scores to LDS; syncthreads; R17's radix-select +
// bitonic runs FROM LDS. Saves one launch + the fscore global round-trip.
// Bit-identical: same values, same fkey/radix/tie/bitonic path.
// ---------------------------------------------------------------------------

#define NTOT_PER_IMG 261888   // sum of H*W*3 over levels
#define ATOT_PER_IMG 4768     // 4*1000 + 768

__constant__ int c_NLVL[5] = {196608, 49152, 12288, 3072, 768};
__constant__ int c_KLVL[5] = {1000, 1000, 1000, 1000, 768};
__constant__ int c_LOFF[5] = {0, 196608, 245760, 258048, 261120};
__constant__ int c_AOFF[5] = {0, 1000, 2000, 3000, 4000};

struct Anch { float cx1[3]; float cy1[3]; };
struct ConvCfg { Anch an[5]; };

// async global->LDS 16B per lane; LDS dest = wave-uniform base + lane*16
// (per-lane pointer s_w + tid*4 floats matches that layout exactly).
__device__ __forceinline__ void gl16(const float* g, float* l) {
  __builtin_amdgcn_global_load_lds(
      (const __attribute__((address_space(1))) void*)g,
      (__attribute__((address_space(3))) void*)l, 16, 0, 0);
}

// ------------------------------ weight transpose ---------------------------
__global__ __launch_bounds__(256) void wtrans(const float* __restrict__ Wsrc,
                                              float* __restrict__ Wt) {
  __shared__ float T[16][17];
  int k0 = blockIdx.x * 16;   // 2304/16 = 144
  int o0 = blockIdx.y * 16;   // 256/16  = 16
  int i = threadIdx.x >> 4, j = threadIdx.x & 15;
  T[i][j] = Wsrc[(size_t)(o0 + i) * 2304 + (k0 + j)];
  __syncthreads();
  Wt[(size_t)(k0 + i) * 256 + (o0 + j)] = T[j][i];
}

// ------------------------------ fused conv (implicit GEMM) -----------------
// EXACT R19 kernel — do not modify (2672us, 72 VGPR, 3 blk/CU, VALU 78.6%).
// R15 structure, 2-ic chunks (128 barriers). 64 px per tile, all 256 oc
// per block, 256 threads, 8oc x 8px per thread.
__global__ __launch_bounds__(256, 2) void conv_gemm(
    const float* __restrict__ f0, const float* __restrict__ f1,
    const float* __restrict__ f2, const float* __restrict__ f3,
    const float* __restrict__ f4, const float* __restrict__ Wt,
    const float* __restrict__ convb, const float* __restrict__ clsw,
    const float* __restrict__ clsb, const float* __restrict__ bboxw,
    const float* __restrict__ bboxb, float* __restrict__ scoresOut,
    float4* __restrict__ boxesOut, ConvCfg cfg) {
  // s_mem: [0,9216) = W dbuf (2 chunks x 2 ics x 2304, gl16 target),
  // [9216,10848) = X dbuf (2 chunks x 2 x 408). Epilogue reuses [0,4160)
  // as t[16px][260] (stride-260 pad).
  __shared__ __align__(16) float s_mem[10848];
  __shared__ float s_Red2[272];                // [16][17] head values
  float* const s_w = s_mem;
  float* const s_x = s_mem + 9216;
  float* const s_tl = s_mem;

  // ---- decode level / image / tile ----
  int b = blockIdx.x;
  const float* feat;
  int lvl, img, tile, H, logW, stride, lvlOff;
  if (b < 2048) {
    lvl = 0; feat = f0; H = 256; logW = 8; stride = 4; lvlOff = 0;
    img = b >> 10; tile = b & 1023;
  } else if (b < 2560) {
    lvl = 1; feat = f1; H = 128; logW = 7; stride = 8; lvlOff = 196608;
    int r = b - 2048; img = r >> 8; tile = r & 255;
  } else if (b < 2688) {
    lvl = 2; feat = f2; H = 64; logW = 6; stride = 16; lvlOff = 245760;
    int r = b - 2560; img = r >> 6; tile = r & 63;
  } else if (b < 2720) {
    lvl = 3; feat = f3; H = 32; logW = 5; stride = 32; lvlOff = 258048;
    int r = b - 2688; img = r >> 4; tile = r & 15;
  } else {
    lvl = 4; feat = f4; H = 16; logW = 4; stride = 64; lvlOff = 261120;
    int r = b - 2720; img = r >> 2; tile = r & 3;
  }
  const int W = H, HW = H * W;
  const int p0 = tile * 64;
  const float* fimg = feat + (size_t)img * 256 * HW;

  const int log2nc = (logW < 6) ? logW : 6;   // ncols = min(W, 64)
  const int ncols = 1 << log2nc;
  const int R = 64 >> log2nc;                 // rows covered by the tile
  const int py0 = p0 >> logW;                 // first image row of tile
  const int c_start = p0 & (W - 1);           // first image col of tile
  const int WIN = ncols + 2;                  // halo row width
  const int NX = (R + 2) * WIN;               // values staged per ic (<=198)

  const int tid = threadIdx.x;
  const int oc0 = (tid >> 3) * 8;   // 32 oc-groups x 8 oc
  const int pxg = tid & 7;          // 8 px-groups x 8 px
  const int px0 = pxg * 8;
  const int trow = px0 >> log2nc;          // thread's row within tile
  const int tcol0 = px0 & (ncols - 1);     // thread's first col within tile

  // ---- X staging descriptor: one halo value per thread per ic ----
  int goffX = -1, loffX = -1;
  if (tid < NX) {
    int lr = tid / WIN;
    int lc = tid - lr * WIN;
    int sy = py0 - 1 + lr;
    int sx = c_start - 1 + lc;
    loffX = lr * 68 + lc;   // row stride 68 floats (272B, 16B-aligned)
    if (sy >= 0 && sy < H && sx >= 0 && sx < W) goffX = sy * W + sx;
  }

  float acc[8][8];
#pragma unroll
  for (int i = 0; i < 8; i++)
#pragma unroll
    for (int p = 0; p < 8; p++) acc[i][p] = 0.f;

  const int t4 = tid << 2;   // per-lane float offset for W staging

  // ---- stage chunk 0 (ics 0,1) into buffer 0 ----
  {
    gl16(Wt + t4, s_w + t4);
    gl16(Wt + 1024 + t4, s_w + 1024 + t4);
    gl16(Wt + 2048 + t4, s_w + 2048 + t4);
    gl16(Wt + 3072 + t4, s_w + 3072 + t4);
    if (tid < 128) gl16(Wt + 4096 + t4, s_w + 4096 + t4);
    if (loffX >= 0) {
      s_x[loffX] = (goffX >= 0) ? fimg[goffX] : 0.f;
      s_x[408 + loffX] = (goffX >= 0) ? fimg[(size_t)HW + goffX] : 0.f;
    }
  }
  __syncthreads();   // drains vmcnt (gl16) + lgkm (ds_write)

  // ---- main K loop: one 2-ic chunk per iteration (128 barriers) ----
#pragma unroll 1
  for (int cc = 0; cc < 128; cc++) {
    const float* wbc = s_w + (cc & 1) * 4608;
    const float* xbc = s_x + (cc & 1) * 816;

    float pxv0, pxv1;
    if (cc < 127) {
      const float* wg = Wt + (size_t)(cc * 2 + 2) * 2304;
      float* wn = s_w + ((cc + 1) & 1) * 4608;
      gl16(wg + t4, wn + t4);
      gl16(wg + 1024 + t4, wn + 1024 + t4);
      gl16(wg + 2048 + t4, wn + 2048 + t4);
      gl16(wg + 3072 + t4, wn + 3072 + t4);
      if (tid < 128) gl16(wg + 4096 + t4, wn + 4096 + t4);
      const float* fnext = fimg + (size_t)(cc * 2 + 2) * HW;
      pxv0 = (goffX >= 0) ? fnext[goffX] : 0.f;
      pxv1 = (goffX >= 0) ? fnext[(size_t)HW + goffX] : 0.f;
    }

    // compute both ics in ascending order (bit-exact chain)
#pragma unroll
    for (int h = 0; h < 2; h++) {
      const float* wb = wbc + h * 2304;
      const float* xb = xbc + h * 408;
#pragma unroll 1
      for (int ky = 0; ky < 3; ky++) {
        const float* xr = xb + (trow + ky) * 68 + tcol0;
        float4 xA = *(const float4*)(xr);
        float4 xB = *(const float4*)(xr + 4);
        float2 xC = *(const float2*)(xr + 8);
        float xw[10] = {xA.x, xA.y, xA.z, xA.w,
                        xB.x, xB.y, xB.z, xB.w, xC.x, xC.y};
        const float* wky = wb + ky * 768 + oc0;
#pragma unroll
        for (int kx = 0; kx < 3; kx++) {
          float4 wa = *(const float4*)(wky + kx * 256);
          float4 wc = *(const float4*)(wky + kx * 256 + 4);
          float wv[8] = {wa.x, wa.y, wa.z, wa.w, wc.x, wc.y, wc.z, wc.w};
#pragma unroll
          for (int i = 0; i < 8; i++)
#pragma unroll
            for (int p = 0; p < 8; p++)
              acc[i][p] = __builtin_fmaf(wv[i], xw[p + kx], acc[i][p]);
        }
      }
    }

    if (cc < 127) {
      float* xn = s_x + ((cc + 1) & 1) * 816;
      if (loffX >= 0) {
        xn[loffX] = pxv0;
        xn[408 + loffX] = pxv1;
      }
    }
    __syncthreads();   // vmcnt: gl16 long since complete; lgkm: X writes
  }

  // ---- epilogue: 4 rounds of 16 px through s_tl (stride 260) ----
  float cb[8];
#pragma unroll
  for (int i = 0; i < 8; i++) cb[i] = convb[oc0 + i];

  const Anch an = cfg.an[lvl];
  const float BCLIP = (float)4.135166556742356;  // log(1000/16)
  const size_t obase = (size_t)img * NTOT_PER_IMG + lvlOff;

#pragma unroll 1
  for (int r = 0; r < 4; r++) {
    if ((pxg >> 1) == r) {   // this thread's 8 px lie in round r
      int pl = px0 - 16 * r; // 0 or 8
#pragma unroll
      for (int p = 0; p < 8; p++) {
        float4 v0 = make_float4(fmaxf(acc[0][p] + cb[0], 0.f),
                                fmaxf(acc[1][p] + cb[1], 0.f),
                                fmaxf(acc[2][p] + cb[2], 0.f),
                                fmaxf(acc[3][p] + cb[3], 0.f));
        float4 v1 = make_float4(fmaxf(acc[4][p] + cb[4], 0.f),
                                fmaxf(acc[5][p] + cb[5], 0.f),
                                fmaxf(acc[6][p] + cb[6], 0.f),
                                fmaxf(acc[7][p] + cb[7], 0.f));
        *(float4*)(s_tl + (pl + p) * 260 + oc0) = v0;
        *(float4*)(s_tl + (pl + p) * 260 + oc0 + 4) = v1;
      }
    }
    __syncthreads();

    // heads: per (px, c) dot over 256 oc in 16x16 two-level order
    if (tid < 240) {
      int px = tid / 15, c = tid - px * 15;
      const float* wr0 = (c < 3) ? (clsw + c * 256) : (bboxw + (c - 3) * 256);
      float bb = (c < 3) ? clsb[c] : bboxb[c - 3];
      const float* trow2 = &s_tl[px * 260];
      float tot = 0.f;
#pragma unroll
      for (int g = 0; g < 16; g++) {
        const float* wr = wr0 + g * 16;
        const float* tr = trow2 + g * 16;
        float s = 0.f;
#pragma unroll
        for (int i = 0; i < 16; i++) s += wr[i] * tr[i];
        tot += s;
      }
      s_Red2[px * 17 + c] = tot + bb;
    }
    __syncthreads();

    // decode: one (pixel, anchor) per thread
    if (tid < 48) {
      int px = tid / 3, a = tid - px * 3;
      int pxl = p0 + r * 16 + px;
      int gy = pxl >> logW, gx = pxl & (W - 1);
      float sc = s_Red2[px * 17 + a];
      float dxv = s_Red2[px * 17 + 3 + a * 4 + 0];
      float dyv = s_Red2[px * 17 + 3 + a * 4 + 1];
      float dwv = s_Red2[px * 17 + 3 + a * 4 + 2];
      float dhv = s_Red2[px * 17 + 3 + a * 4 + 3];
      float sx = (float)(gx * stride), sy = (float)(gy * stride);
      float x1 = __fadd_rn(sx, an.cx1[a]);
      float x2 = __fsub_rn(sx, an.cx1[a]);
      float y1 = __fadd_rn(sy, an.cy1[a]);
      float y2 = __fsub_rn(sy, an.cy1[a]);
      float wdt = __fadd_rn(__fsub_rn(x2, x1), 1.0f);
      float hgt = __fadd_rn(__fsub_rn(y2, y1), 1.0f);
      float ctx = __fadd_rn(x1, __fmul_rn(0.5f, wdt));
      float cty = __fadd_rn(y1, __fmul_rn(0.5f, hgt));
      float dw = fminf(dwv, BCLIP), dh = fminf(dhv, BCLIP);
      float pcx = __fadd_rn(__fmul_rn(dxv, wdt), ctx);
      float pcy = __fadd_rn(__fmul_rn(dyv, hgt), cty);
      float pw = __fmul_rn(expf(dw), wdt);
      float ph = __fmul_rn(expf(dh), hgt);
      float hw = __fmul_rn(0.5f, pw), hh = __fmul_rn(0.5f, ph);
      float bx1 = __fsub_rn(pcx, hw);
      float by1 = __fsub_rn(pcy, hh);
      float bx2 = __fsub_rn(__fadd_rn(pcx, hw), 1.0f);
      float by2 = __fsub_rn(__fadd_rn(pcy, hh), 1.0f);
      bx1 = fminf(fmaxf(bx1, 0.f), 1023.f);
      by1 = fminf(fmaxf(by1, 0.f), 1023.f);
      bx2 = fminf(fmaxf(bx2, 0.f), 1023.f);
      by2 = fminf(fmaxf(by2, 0.f), 1023.f);
      size_t o = obase + (size_t)pxl * 3 + a;
      scoresOut[o] = sc;
      boxesOut[o] = make_float4(bx1, by1, bx2, by2);
    }
    __syncthreads();
  }
}

// ------------------------------ top-k helpers ------------------------------
__device__ __forceinline__ unsigned fkeyu(unsigned b) {
  return (b & 0x80000000u) ? ~b : (b | 0x80000000u);
}
__device__ __forceinline__ unsigned fkey(float f) {
  return fkeyu(__float_as_uint(f));
}
__device__ __forceinline__ float funkey(unsigned u) {
  unsigned b = (u & 0x80000000u) ? (u & 0x7fffffffu) : ~u;
  return __uint_as_float(b);
}

// Per-level top-k (R17 version — frozen; R18's two-phase split regressed).
// Exact lax.top_k: value desc, index asc on ties. Radix-select threshold,
// bisect index cut for boundary ties, bitonic-sort packed (key, ~idx).
// uint4 scans + 16-way replicated histogram.
__global__ __launch_bounds__(1024) void topk_level(
    const float* __restrict__ scoresIn, const float4* __restrict__ boxesIn,
    float* __restrict__ scoresOut, float4* __restrict__ boxesOut) {
  __shared__ unsigned long long keys[1024];
  __shared__ unsigned hist[256 * 16];   // 16 replicas: bin*16 + (tid&15)
  __shared__ unsigned s_hsum[256];
  __shared__ unsigned s_comm[4];
  const int lvl = blockIdx.x, img = blockIdx.y;
  const int N = c_NLVL[lvl], k = c_KLVL[lvl];
  const float* src = scoresIn + (size_t)img * NTOT_PER_IMG + c_LOFF[lvl];
  const float4* bsrc = boxesIn + (size_t)img * NTOT_PER_IMG + c_LOFF[lvl];
  const int tid = threadIdx.x;
  const int rep = tid & 15;
  const uint4* src4 = (const uint4*)src;   // all bases/offsets 16B-aligned
  const int N4 = N >> 2;

  unsigned pref = 0, pmask = 0, krem = (unsigned)k, cntT = 0;
  for (int pass = 3; pass >= 0; pass--) {
    int shift = pass * 8;
    for (int z = tid; z < 4096; z += 1024) hist[z] = 0;
    __syncthreads();
    for (int i = tid; i < N4; i += 1024) {
      uint4 v = src4[i];
      unsigned u0 = fkeyu(v.x), u1 = fkeyu(v.y);
      unsigned u2 = fkeyu(v.z), u3 = fkeyu(v.w);
      if ((u0 & pmask) == pref)
        atomicAdd(&hist[((u0 >> shift) & 255) * 16 + rep], 1u);
      if ((u1 & pmask) == pref)
        atomicAdd(&hist[((u1 >> shift) & 255) * 16 + rep], 1u);
      if ((u2 & pmask) == pref)
        atomicAdd(&hist[((u2 >> shift) & 255) * 16 + rep], 1u);
      if ((u3 & pmask) == pref)
        atomicAdd(&hist[((u3 >> shift) & 255) * 16 + rep], 1u);
    }
    __syncthreads();
    if (tid < 256) {
      unsigned s = 0;
#pragma unroll
      for (int r2 = 0; r2 < 16; r2++) s += hist[tid * 16 + r2];
      s_hsum[tid] = s;
    }
    __syncthreads();
    if (tid == 0) {
      unsigned cum = 0;
      for (int d = 255; d >= 0; d--) {
        unsigned c = s_hsum[d];
        if (cum + c >= krem) {
          s_comm[0] = krem - cum; s_comm[1] = c; s_comm[2] = (unsigned)d;
          break;
        }
        cum += c;
      }
    }
    __syncthreads();
    krem = s_comm[0]; cntT = s_comm[1];
    pref |= s_comm[2] << shift;
    pmask |= 0xFFu << shift;
    __syncthreads();
  }
  const unsigned T = pref, r = krem;
  unsigned m = (unsigned)N;
  if (r < cntT) {  // boundary ties: smallest r indices among {u == T}
    unsigned lo = 0, hi = (unsigned)N;
    while (lo < hi) {
      unsigned mid = (lo + hi) >> 1;
      if (tid == 0) s_comm[3] = 0;
      __syncthreads();
      for (unsigned i = tid; i < mid; i += 1024)
        if (fkey(src[i]) == T) atomicAdd(&s_comm[3], 1u);
      __syncthreads();
      unsigned c = s_comm[3];
      __syncthreads();
      if (c >= r) hi = mid; else lo = mid + 1;
    }
    m = lo;
  }
  if (tid == 0) s_comm[3] = 0;
  __syncthreads();
  for (int i = tid; i < N4; i += 1024) {
    uint4 v = src4[i];
#pragma unroll
    for (int j = 0; j < 4; j++) {
      unsigned bu = (j == 0) ? v.x : (j == 1) ? v.y : (j == 2) ? v.z : v.w;
      unsigned u = fkeyu(bu);
      unsigned idx = (unsigned)(i * 4 + j);
      if (u > T || (u == T && idx < m)) {
        unsigned p = atomicAdd(&s_comm[3], 1u);
        if (p < 1024)
          keys[p] = ((unsigned long long)u << 32) | (unsigned)(~idx);
      }
    }
  }
  __syncthreads();
  if (tid >= k) keys[tid] = 0ull;  // pad; sorts to the end
  __syncthreads();
  // bitonic sort, descending
  for (unsigned k2 = 2; k2 <= 1024; k2 <<= 1) {
    for (unsigned j = k2 >> 1; j > 0; j >>= 1) {
      unsigned i = tid, ixj = i ^ j;
      if (ixj > i) {
        unsigned long long a = keys[i], b = keys[ixj];
        bool sw = ((i & k2) == 0) ? (a < b) : (a > b);
        if (sw) { keys[i] = b; keys[ixj] = a; }
      }
      __syncthreads();
    }
  }
  if (tid < k) {
    unsigned long long key = keys[tid];
    unsigned u = (unsigned)(key >> 32);
    unsigned idx = ~((unsigned)key);
    float sc = funkey(u);
    float4 b = bsrc[idx];
    scoresOut[(size_t)img * ATOT_PER_IMG + c_AOFF[lvl] + tid] = sc;
    boxesOut[(size_t)img * ATOT_PER_IMG + c_AOFF[lvl] + tid] = b;
  }
}

// ------------------------------ NMS matrix ---------------------------------
__global__ __launch_bounds__(256) void nms_matrix(
    const float4* __restrict__ allb, unsigned long long* __restrict__ supp) {
  int lvl = blockIdx.x, img = blockIdx.y, rb = blockIdx.z;
  int k = c_KLVL[lvl];
  int task = img * 5 + lvl;
  const float4* src = allb + (size_t)img * ATOT_PER_IMG + c_AOFF[lvl];
  __shared__ float4 bb[1000];
  __shared__ float ar[1000];
  for (int j = threadIdx.x; j < k; j += 256) {
    float4 b = src[j];
    bb[j] = b;
    ar[j] = __fmul_rn(__fsub_rn(b.z, b.x), __fsub_rn(b.w, b.y));
  }
  __syncthreads();
  int i = rb * 256 + threadIdx.x;
  if (i < k) {
    float4 bi = bb[i];
    float ai = ar[i];
    unsigned long long* row = supp + ((size_t)task * 1024 + i) * 16;
    int jw0 = i >> 6;
    for (int jw = 0; jw < jw0; jw++) row[jw] = 0ull;
    for (int jw = jw0; jw < 16; jw++) {
      unsigned long long bits = 0;
      int jbase = jw * 64;
      for (int jj = 0; jj < 64; jj++) {
        int j = jbase + jj;
        if (j > i && j < k) {
          float4 bj = bb[j];
          float ltx = fmaxf(bi.x, bj.x), lty = fmaxf(bi.y, bj.y);
          float rbx = fminf(bi.z, bj.z), rby = fminf(bi.w, bj.w);
          float wx = fmaxf(__fsub_rn(rbx, ltx), 0.f);
          float wy = fmaxf(__fsub_rn(rby, lty), 0.f);
          float inter = __fmul_rn(wx, wy);
          float den = __fadd_rn(__fsub_rn(__fadd_rn(ai, ar[j]), inter), 1e-9f);
          if (__fdiv_rn(inter, den) > 0.7f) bits |= 1ull << jj;
        }
      }
      row[jw] = bits;
    }
  }
}

// ------------------------------ fused NMS-scan + final top-k ---------------
// One block per image (1024 thr). Waves 0-4 each run one level's greedy
// NMS scan (verbatim wave-shuffle port of nms_scan), writing the masked
// scores into LDS; after syncthreads, the R17 radix-select + bitonic runs
// from LDS. Values and selection order identical to the split kernels.
__global__ __launch_bounds__(1024) void nms_topk_final(
    const float* __restrict__ topS, const unsigned long long* __restrict__ supp,
    const float4* __restrict__ boxesIn, float* __restrict__ finalOut) {
  __shared__ float fsc[ATOT_PER_IMG];   // masked scores (19KB)
  __shared__ unsigned long long keys[1024];
  __shared__ unsigned hist[256 * 16];
  __shared__ unsigned s_hsum[256];
  __shared__ unsigned s_comm[4];
  const int img = blockIdx.x;
  const int tid = threadIdx.x;
  const int wave = tid >> 6, lane = tid & 63;

  // ---- phase 1: per-level NMS scan (waves 0-4) ----
  if (wave < 5) {
    const int lvl = wave;
    const int k = c_KLVL[lvl];
    const int task = img * 5 + lvl;
    const unsigned long long* base = supp + (size_t)task * 1024 * 16;
    unsigned long long rem = 0, keep = 0;  // lane l<16 holds word l
    for (int b0 = 0; b0 < k; b0 += 16) {
      unsigned long long buf[16];
#pragma unroll
      for (int t = 0; t < 16; t++) {
        int i = b0 + t;
        buf[t] = (lane < 16 && i < k) ? base[(size_t)i * 16 + lane] : 0ull;
      }
#pragma unroll
      for (int t = 0; t < 16; t++) {
        int i = b0 + t;
        if (i >= k) break;
        int wi = i >> 6, bi = i & 63;
        unsigned long long rw = __shfl(rem, wi);
        if (!((rw >> bi) & 1ull)) {  // i survives: suppress its row
          rem |= buf[t];
          if (lane == wi) keep |= (1ull << bi);
        }
      }
    }
    const float* ts = topS + (size_t)img * ATOT_PER_IMG + c_AOFF[lvl];
    float* fs = fsc + c_AOFF[lvl];
    for (int i = lane; i < k; i += 64) {
      int wi = i >> 6;
      unsigned long long kw = __shfl(keep, wi);
      fs[i] = ((kw >> (i & 63)) & 1ull) ? ts[i] : -1e9f;
    }
  }
  __syncthreads();

  // ---- phase 2: exact top-1000 of fsc (R17 path, LDS source) ----
  const int N = ATOT_PER_IMG, k = 1000;
  const float4* bsrc = boxesIn + (size_t)img * ATOT_PER_IMG;
  const int rep = tid & 15;

  unsigned pref = 0, pmask = 0, krem = (unsigned)k, cntT = 0;
  for (int pass = 3; pass >= 0; pass--) {
    int shift = pass * 8;
    for (int z = tid; z < 4096; z += 1024) hist[z] = 0;
    __syncthreads();
    for (int i = tid; i < N; i += 1024) {
      unsigned u = fkey(fsc[i]);
      if ((u & pmask) == pref)
        atomicAdd(&hist[((u >> shift) & 255) * 16 + rep], 1u);
    }
    __syncthreads();
    if (tid < 256) {
      unsigned s = 0;
#pragma unroll
      for (int r2 = 0; r2 < 16; r2++) s += hist[tid * 16 + r2];
      s_hsum[tid] = s;
    }
    __syncthreads();
    if (tid == 0) {
      unsigned cum = 0;
      for (int d = 255; d >= 0; d--) {
        unsigned c = s_hsum[d];
        if (cum + c >= krem) {
          s_comm[0] = krem - cum; s_comm[1] = c; s_comm[2] = (unsigned)d;
          break;
        }
        cum += c;
      }
    }
    __syncthreads();
    krem = s_comm[0]; cntT = s_comm[1];
    pref |= s_comm[2] << shift;
    pmask |= 0xFFu << shift;
    __syncthreads();
  }
  const unsigned T = pref, r = krem;
  unsigned m = (unsigned)N;
  if (r < cntT) {  // boundary ties: smallest r indices among {u == T}
    unsigned lo = 0, hi = (unsigned)N;
    while (lo < hi) {
      unsigned mid = (lo + hi) >> 1;
      if (tid == 0) s_comm[3] = 0;
      __syncthreads();
      for (unsigned i = tid; i < mid; i += 1024)
        if (fkey(fsc[i]) == T) atomicAdd(&s_comm[3], 1u);
      __syncthreads();
      unsigned c = s_comm[3];
      __syncthreads();
      if (c >= r) hi = mid; else lo = mid + 1;
    }
    m = lo;
  }
  if (tid == 0) s_comm[3] = 0;
  __syncthreads();
  for (int i = tid; i < N; i += 1024) {
    unsigned u = fkey(fsc[i]);
    unsigned idx = (unsigned)i;
    if (u > T || (u == T && idx < m)) {
      unsigned p = atomicAdd(&s_comm[3], 1u);
      if (p < 1024)
        keys[p] = ((unsigned long long)u << 32) | (unsigned)(~idx);
    }
  }
  __syncthreads();
  if (tid >= k) keys[tid] = 0ull;  // pad; sorts to the end
  __syncthreads();
  for (unsigned k2 = 2; k2 <= 1024; k2 <<= 1) {
    for (unsigned j = k2 >> 1; j > 0; j >>= 1) {
      unsigned i = tid, ixj = i ^ j;
      if (ixj > i) {
        unsigned long long a = keys[i], b = keys[ixj];
        bool sw = ((i & k2) == 0) ? (a < b) : (a > b);
        if (sw) { keys[i] = b; keys[ixj] = a; }
      }
      __syncthreads();
    }
  }
  if (tid < k) {
    unsigned long long key = keys[tid];
    unsigned u = (unsigned)(key >> 32);
    unsigned idx = ~((unsigned)key);
    float sc = funkey(u);
    float4 b = bsrc[idx];
    float* o = finalOut + ((size_t)img * 1000 + tid) * 5;
    o[0] = b.x; o[1] = b.y; o[2] = b.z; o[3] = b.w; o[4] = sc;
  }
}

// ------------------------------ host ---------------------------------------
static Anch mkAnch(double size) {
  Anch a;
  const double R[3] = {0.5, 1.0, 2.0};
  for (int i = 0; i < 3; i++) {
    double w = size * sqrt(1.0 / R[i]);
    double h = size * sqrt(R[i]);
    a.cx1[i] = (float)(-w / 2.0);
    a.cy1[i] = (float)(-h / 2.0);
  }
  return a;
}

extern "C" void kernel_launch(void* const* d_in, const int* in_sizes, int n_in,
                              void* d_out, int out_size, void* d_ws,
                              size_t ws_size, hipStream_t stream) {
  (void)in_sizes; (void)n_in; (void)out_size; (void)ws_size;
  const float* f0 = (const float*)d_in[0];
  const float* f1 = (const float*)d_in[1];
  const float* f2 = (const float*)d_in[2];
  const float* f3 = (const float*)d_in[3];
  const float* f4 = (const float*)d_in[4];
  const float* conv_w = (const float*)d_in[5];
  const float* conv_b = (const float*)d_in[6];
  const float* cls_w  = (const float*)d_in[7];
  const float* cls_b  = (const float*)d_in[8];
  const float* bbox_w = (const float*)d_in[9];
  const float* bbox_b = (const float*)d_in[10];
  float* out = (float*)d_out;

  // workspace layout (floats), all 16B-aligned; total ~14.4 MB
  float* wsf = (float*)d_ws;
  float* Wt     = wsf;                      // 589824
  float* scores = Wt + 589824;              // 2*261888
  float* boxes  = scores + 2 * NTOT_PER_IMG;       // 2*261888*4
  float* topS   = boxes + (size_t)2 * NTOT_PER_IMG * 4;  // 2*4768
  float* allb   = topS + 2 * ATOT_PER_IMG;         // 2*4768*4
  float* fscore = allb + (size_t)2 * ATOT_PER_IMG * 4;   // 2*4768 (unused)
  unsigned long long* supp =
      (unsigned long long*)(fscore + 2 * ATOT_PER_IMG);  // 10*1024*16 u64

  wtrans<<<dim3(144, 16), 256, 0, stream>>>(conv_w, Wt);

  ConvCfg cfg;
  const double SZ[5] = {32, 64, 128, 256, 512};
  for (int l = 0; l < 5; l++) cfg.an[l] = mkAnch(SZ[l]);

  conv_gemm<<<2728, 256, 0, stream>>>(f0, f1, f2, f3, f4, Wt, conv_b, cls_w,
                                      cls_b, bbox_w, bbox_b, scores,
                                      (float4*)boxes, cfg);

  topk_level<<<dim3(5, 2), 1024, 0, stream>>>(
      scores, (const float4*)boxes, topS, (float4*)allb);
  nms_matrix<<<dim3(5, 2, 4), 256, 0, stream>>>((const float4*)allb, supp);
  nms_topk_final<<<2, 1024, 0, stream>>>(topS, supp, (const float4*)allb,
                                         out);
}

// Round 15
// 3080.370 us; speedup vs baseline: 1.0576x; 1.0576x over previous
//
#include <hip/hip_runtime.h>
#include <cmath>

// ---------------------------------------------------------------------------
// RPN head on MI355X. fp32 throughout; conv FMA chain order (ic,ky,kx asc,
// fmaf(w,x,acc)) and the head's 16x16 two-level reduction are bit-exact vs
// the np reference (absmax 0.0 every round) — preserve both exactly.
//
// FINAL = R19 (best verified: 3102us total, conv 2672us).
// Conv history (conv µs): R6 3277 / R7 spill / R8 3370 / R9 3210 / R10
// spill (cap) / R11 3100 / R12 3125 / R13 3460 / R14 4250 / R15 2795 /
// R16 3200 / R19 2672 BEST. Tail: R17 single-phase topk best; R18
// two-phase split regressed; R20 nms+final fusion regressed (5/16 waves
// busy in scan phase; fscore round-trip was L2-resident anyway).
// Conv = measured local optimum: occupancy wall (132-reg acc tile -> 3
// waves/SIMD; caps below demand spill), 8x8 tile optimum (R14), ILP via
// persistent regs loses occupancy (R9/R13/R16), barriers amortized to the
// LDS limit (R19: 2-ic chunks, 49.5KB, 3 blk/CU; 3-ic would drop to 2),
// bank conflicts/barrier type off critical path (R12).
// ---------------------------------------------------------------------------

#define NTOT_PER_IMG 261888   // sum of H*W*3 over levels
#define ATOT_PER_IMG 4768     // 4*1000 + 768

__constant__ int c_NLVL[5] = {196608, 49152, 12288, 3072, 768};
__constant__ int c_KLVL[5] = {1000, 1000, 1000, 1000, 768};
__constant__ int c_LOFF[5] = {0, 196608, 245760, 258048, 261120};
__constant__ int c_AOFF[5] = {0, 1000, 2000, 3000, 4000};

struct Anch { float cx1[3]; float cy1[3]; };
struct ConvCfg { Anch an[5]; };

// async global->LDS 16B per lane; LDS dest = wave-uniform base + lane*16
// (per-lane pointer s_w + tid*4 floats matches that layout exactly).
__device__ __forceinline__ void gl16(const float* g, float* l) {
  __builtin_amdgcn_global_load_lds(
      (const __attribute__((address_space(1))) void*)g,
      (__attribute__((address_space(3))) void*)l, 16, 0, 0);
}

// ------------------------------ weight transpose ---------------------------
__global__ __launch_bounds__(256) void wtrans(const float* __restrict__ Wsrc,
                                              float* __restrict__ Wt) {
  __shared__ float T[16][17];
  int k0 = blockIdx.x * 16;   // 2304/16 = 144
  int o0 = blockIdx.y * 16;   // 256/16  = 16
  int i = threadIdx.x >> 4, j = threadIdx.x & 15;
  T[i][j] = Wsrc[(size_t)(o0 + i) * 2304 + (k0 + j)];
  __syncthreads();
  Wt[(size_t)(k0 + i) * 256 + (o0 + j)] = T[j][i];
}

// ------------------------------ fused conv (implicit GEMM) -----------------
// R15 structure, 2-ic chunks. Block tiles: L0 [0,2048) L1 [2048,2560)
// L2 [2560,2688) L3 [2688,2720) L4 [2720,2728); 64 px per tile, all 256
// oc per block, 256 threads, 8oc x 8px per thread. ncols = min(W,64),
// R = 64/ncols rows; X halo (R+2) x (ncols+2), block-cooperative staging.
__global__ __launch_bounds__(256, 2) void conv_gemm(
    const float* __restrict__ f0, const float* __restrict__ f1,
    const float* __restrict__ f2, const float* __restrict__ f3,
    const float* __restrict__ f4, const float* __restrict__ Wt,
    const float* __restrict__ convb, const float* __restrict__ clsw,
    const float* __restrict__ clsb, const float* __restrict__ bboxw,
    const float* __restrict__ bboxb, float* __restrict__ scoresOut,
    float4* __restrict__ boxesOut, ConvCfg cfg) {
  // s_mem: [0,9216) = W dbuf (2 chunks x 2 ics x 2304, gl16 target),
  // [9216,10848) = X dbuf (2 chunks x 2 x 408). Epilogue (after final
  // __syncthreads) reuses [0,4160) as t[16px][260] (stride-260 pad).
  __shared__ __align__(16) float s_mem[10848];
  __shared__ float s_Red2[272];                // [16][17] head values
  float* const s_w = s_mem;
  float* const s_x = s_mem + 9216;
  float* const s_tl = s_mem;

  // ---- decode level / image / tile ----
  int b = blockIdx.x;
  const float* feat;
  int lvl, img, tile, H, logW, stride, lvlOff;
  if (b < 2048) {
    lvl = 0; feat = f0; H = 256; logW = 8; stride = 4; lvlOff = 0;
    img = b >> 10; tile = b & 1023;
  } else if (b < 2560) {
    lvl = 1; feat = f1; H = 128; logW = 7; stride = 8; lvlOff = 196608;
    int r = b - 2048; img = r >> 8; tile = r & 255;
  } else if (b < 2688) {
    lvl = 2; feat = f2; H = 64; logW = 6; stride = 16; lvlOff = 245760;
    int r = b - 2560; img = r >> 6; tile = r & 63;
  } else if (b < 2720) {
    lvl = 3; feat = f3; H = 32; logW = 5; stride = 32; lvlOff = 258048;
    int r = b - 2688; img = r >> 4; tile = r & 15;
  } else {
    lvl = 4; feat = f4; H = 16; logW = 4; stride = 64; lvlOff = 261120;
    int r = b - 2720; img = r >> 2; tile = r & 3;
  }
  const int W = H, HW = H * W;
  const int p0 = tile * 64;
  const float* fimg = feat + (size_t)img * 256 * HW;

  const int log2nc = (logW < 6) ? logW : 6;   // ncols = min(W, 64)
  const int ncols = 1 << log2nc;
  const int R = 64 >> log2nc;                 // rows covered by the tile
  const int py0 = p0 >> logW;                 // first image row of tile
  const int c_start = p0 & (W - 1);           // first image col of tile
  const int WIN = ncols + 2;                  // halo row width
  const int NX = (R + 2) * WIN;               // values staged per ic (<=198)

  const int tid = threadIdx.x;
  const int oc0 = (tid >> 3) * 8;   // 32 oc-groups x 8 oc
  const int pxg = tid & 7;          // 8 px-groups x 8 px
  const int px0 = pxg * 8;
  const int trow = px0 >> log2nc;          // thread's row within tile
  const int tcol0 = px0 & (ncols - 1);     // thread's first col within tile

  // ---- X staging descriptor: one halo value per thread per ic ----
  int goffX = -1, loffX = -1;
  if (tid < NX) {
    int lr = tid / WIN;
    int lc = tid - lr * WIN;
    int sy = py0 - 1 + lr;
    int sx = c_start - 1 + lc;
    loffX = lr * 68 + lc;   // row stride 68 floats (272B, 16B-aligned)
    if (sy >= 0 && sy < H && sx >= 0 && sx < W) goffX = sy * W + sx;
  }

  float acc[8][8];
#pragma unroll
  for (int i = 0; i < 8; i++)
#pragma unroll
    for (int p = 0; p < 8; p++) acc[i][p] = 0.f;

  const int t4 = tid << 2;   // per-lane float offset for W staging

  // ---- stage chunk 0 (ics 0,1) into buffer 0 ----
  {
    // W: 4608 floats = 1152 float4; 4 full rounds + 128 extra
    gl16(Wt + t4, s_w + t4);
    gl16(Wt + 1024 + t4, s_w + 1024 + t4);
    gl16(Wt + 2048 + t4, s_w + 2048 + t4);
    gl16(Wt + 3072 + t4, s_w + 3072 + t4);
    if (tid < 128) gl16(Wt + 4096 + t4, s_w + 4096 + t4);
    if (loffX >= 0) {
      s_x[loffX] = (goffX >= 0) ? fimg[goffX] : 0.f;
      s_x[408 + loffX] = (goffX >= 0) ? fimg[(size_t)HW + goffX] : 0.f;
    }
  }
  __syncthreads();   // drains vmcnt (gl16) + lgkm (ds_write)

  // ---- main K loop: one 2-ic chunk per iteration (128 barriers) ----
#pragma unroll 1
  for (int cc = 0; cc < 128; cc++) {
    const float* wbc = s_w + (cc & 1) * 4608;
    const float* xbc = s_x + (cc & 1) * 816;

    // issue next chunk's loads NOW: W via async DMA (no VGPR round-trip),
    // X to two registers. ~2300 issue-cycles of FMA cover the latency.
    float pxv0, pxv1;
    if (cc < 127) {
      const float* wg = Wt + (size_t)(cc * 2 + 2) * 2304;
      float* wn = s_w + ((cc + 1) & 1) * 4608;
      gl16(wg + t4, wn + t4);
      gl16(wg + 1024 + t4, wn + 1024 + t4);
      gl16(wg + 2048 + t4, wn + 2048 + t4);
      gl16(wg + 3072 + t4, wn + 3072 + t4);
      if (tid < 128) gl16(wg + 4096 + t4, wn + 4096 + t4);
      const float* fnext = fimg + (size_t)(cc * 2 + 2) * HW;
      pxv0 = (goffX >= 0) ? fnext[goffX] : 0.f;
      pxv1 = (goffX >= 0) ? fnext[(size_t)HW + goffX] : 0.f;
    }

    // compute both ics in ascending order (bit-exact chain). Per ky read
    // a 10-float window, share across kx; W from LDS (broadcast within
    // 8-lane oc-group). ky serial -> bounded in-flight reads.
#pragma unroll
    for (int h = 0; h < 2; h++) {
      const float* wb = wbc + h * 2304;
      const float* xb = xbc + h * 408;
#pragma unroll 1
      for (int ky = 0; ky < 3; ky++) {
        const float* xr = xb + (trow + ky) * 68 + tcol0;
        float4 xA = *(const float4*)(xr);
        float4 xB = *(const float4*)(xr + 4);
        float2 xC = *(const float2*)(xr + 8);
        float xw[10] = {xA.x, xA.y, xA.z, xA.w,
                        xB.x, xB.y, xB.z, xB.w, xC.x, xC.y};
        const float* wky = wb + ky * 768 + oc0;
#pragma unroll
        for (int kx = 0; kx < 3; kx++) {
          float4 wa = *(const float4*)(wky + kx * 256);
          float4 wc = *(const float4*)(wky + kx * 256 + 4);
          float wv[8] = {wa.x, wa.y, wa.z, wa.w, wc.x, wc.y, wc.z, wc.w};
#pragma unroll
          for (int i = 0; i < 8; i++)
#pragma unroll
            for (int p = 0; p < 8; p++)
              acc[i][p] = __builtin_fmaf(wv[i], xw[p + kx], acc[i][p]);
        }
      }
    }

    if (cc < 127) {
      float* xn = s_x + ((cc + 1) & 1) * 816;
      if (loffX >= 0) {
        xn[loffX] = pxv0;
        xn[408 + loffX] = pxv1;
      }
    }
    __syncthreads();   // vmcnt: gl16 long since complete; lgkm: X writes
  }

  // ---- epilogue: 4 rounds of 16 px through s_tl (stride 260) ----
  float cb[8];
#pragma unroll
  for (int i = 0; i < 8; i++) cb[i] = convb[oc0 + i];

  const Anch an = cfg.an[lvl];
  const float BCLIP = (float)4.135166556742356;  // log(1000/16)
  const size_t obase = (size_t)img * NTOT_PER_IMG + lvlOff;

#pragma unroll 1
  for (int r = 0; r < 4; r++) {
    if ((pxg >> 1) == r) {   // this thread's 8 px lie in round r
      int pl = px0 - 16 * r; // 0 or 8
#pragma unroll
      for (int p = 0; p < 8; p++) {
        float4 v0 = make_float4(fmaxf(acc[0][p] + cb[0], 0.f),
                                fmaxf(acc[1][p] + cb[1], 0.f),
                                fmaxf(acc[2][p] + cb[2], 0.f),
                                fmaxf(acc[3][p] + cb[3], 0.f));
        float4 v1 = make_float4(fmaxf(acc[4][p] + cb[4], 0.f),
                                fmaxf(acc[5][p] + cb[5], 0.f),
                                fmaxf(acc[6][p] + cb[6], 0.f),
                                fmaxf(acc[7][p] + cb[7], 0.f));
        *(float4*)(s_tl + (pl + p) * 260 + oc0) = v0;
        *(float4*)(s_tl + (pl + p) * 260 + oc0 + 4) = v1;
      }
    }
    __syncthreads();

    // heads: per (px, c) dot over 256 oc in 16x16 two-level order
    if (tid < 240) {
      int px = tid / 15, c = tid - px * 15;
      const float* wr0 = (c < 3) ? (clsw + c * 256) : (bboxw + (c - 3) * 256);
      float bb = (c < 3) ? clsb[c] : bboxb[c - 3];
      const float* trow2 = &s_tl[px * 260];
      float tot = 0.f;
#pragma unroll
      for (int g = 0; g < 16; g++) {
        const float* wr = wr0 + g * 16;
        const float* tr = trow2 + g * 16;
        float s = 0.f;
#pragma unroll
        for (int i = 0; i < 16; i++) s += wr[i] * tr[i];
        tot += s;
      }
      s_Red2[px * 17 + c] = tot + bb;
    }
    __syncthreads();

    // decode: one (pixel, anchor) per thread
    if (tid < 48) {
      int px = tid / 3, a = tid - px * 3;
      int pxl = p0 + r * 16 + px;
      int gy = pxl >> logW, gx = pxl & (W - 1);
      float sc = s_Red2[px * 17 + a];
      float dxv = s_Red2[px * 17 + 3 + a * 4 + 0];
      float dyv = s_Red2[px * 17 + 3 + a * 4 + 1];
      float dwv = s_Red2[px * 17 + 3 + a * 4 + 2];
      float dhv = s_Red2[px * 17 + 3 + a * 4 + 3];
      float sx = (float)(gx * stride), sy = (float)(gy * stride);
      float x1 = __fadd_rn(sx, an.cx1[a]);
      float x2 = __fsub_rn(sx, an.cx1[a]);
      float y1 = __fadd_rn(sy, an.cy1[a]);
      float y2 = __fsub_rn(sy, an.cy1[a]);
      float wdt = __fadd_rn(__fsub_rn(x2, x1), 1.0f);
      float hgt = __fadd_rn(__fsub_rn(y2, y1), 1.0f);
      float ctx = __fadd_rn(x1, __fmul_rn(0.5f, wdt));
      float cty = __fadd_rn(y1, __fmul_rn(0.5f, hgt));
      float dw = fminf(dwv, BCLIP), dh = fminf(dhv, BCLIP);
      float pcx = __fadd_rn(__fmul_rn(dxv, wdt), ctx);
      float pcy = __fadd_rn(__fmul_rn(dyv, hgt), cty);
      float pw = __fmul_rn(expf(dw), wdt);
      float ph = __fmul_rn(expf(dh), hgt);
      float hw = __fmul_rn(0.5f, pw), hh = __fmul_rn(0.5f, ph);
      float bx1 = __fsub_rn(pcx, hw);
      float by1 = __fsub_rn(pcy, hh);
      float bx2 = __fsub_rn(__fadd_rn(pcx, hw), 1.0f);
      float by2 = __fsub_rn(__fadd_rn(pcy, hh), 1.0f);
      bx1 = fminf(fmaxf(bx1, 0.f), 1023.f);
      by1 = fminf(fmaxf(by1, 0.f), 1023.f);
      bx2 = fminf(fmaxf(bx2, 0.f), 1023.f);
      by2 = fminf(fmaxf(by2, 0.f), 1023.f);
      size_t o = obase + (size_t)pxl * 3 + a;
      scoresOut[o] = sc;
      boxesOut[o] = make_float4(bx1, by1, bx2, by2);
    }
    __syncthreads();
  }
}

// ------------------------------ top-k (R17 version) ------------------------
__device__ __forceinline__ unsigned fkeyu(unsigned b) {
  return (b & 0x80000000u) ? ~b : (b | 0x80000000u);
}
__device__ __forceinline__ unsigned fkey(float f) {
  return fkeyu(__float_as_uint(f));
}
__device__ __forceinline__ float funkey(unsigned u) {
  unsigned b = (u & 0x80000000u) ? (u & 0x7fffffffu) : ~u;
  return __uint_as_float(b);
}

// Exact lax.top_k: value desc, index asc on ties. Radix-select threshold,
// bisect index cut for boundary ties, bitonic-sort packed (key, ~idx).
// uint4 scans + 16-way replicated histogram (fp32 exponent clustering puts
// ~half the keys in 2-3 bins -> replication cuts 64-way same-address
// serialization to 4-way).
template <bool FINAL>
__global__ __launch_bounds__(1024) void topk_kernel(
    const float* __restrict__ scoresIn, const float4* __restrict__ boxesIn,
    float* __restrict__ scoresOut, float4* __restrict__ boxesOut,
    float* __restrict__ finalOut) {
  __shared__ unsigned long long keys[1024];
  __shared__ unsigned hist[256 * 16];   // 16 replicas: bin*16 + (tid&15)
  __shared__ unsigned s_hsum[256];
  __shared__ unsigned s_comm[4];
  int lvl = 0, img, N, k;
  const float* src;
  const float4* bsrc;
  if (FINAL) {
    img = blockIdx.x; N = ATOT_PER_IMG; k = 1000;
    src = scoresIn + (size_t)img * ATOT_PER_IMG;
    bsrc = boxesIn + (size_t)img * ATOT_PER_IMG;
  } else {
    lvl = blockIdx.x; img = blockIdx.y;
    N = c_NLVL[lvl]; k = c_KLVL[lvl];
    src = scoresIn + (size_t)img * NTOT_PER_IMG + c_LOFF[lvl];
    bsrc = boxesIn + (size_t)img * NTOT_PER_IMG + c_LOFF[lvl];
  }
  const int tid = threadIdx.x;
  const int rep = tid & 15;
  const uint4* src4 = (const uint4*)src;   // all bases/offsets 16B-aligned
  const int N4 = N >> 2;

  unsigned pref = 0, pmask = 0, krem = (unsigned)k, cntT = 0;
  for (int pass = 3; pass >= 0; pass--) {
    int shift = pass * 8;
    for (int z = tid; z < 4096; z += 1024) hist[z] = 0;
    __syncthreads();
    for (int i = tid; i < N4; i += 1024) {
      uint4 v = src4[i];
      unsigned u0 = fkeyu(v.x), u1 = fkeyu(v.y);
      unsigned u2 = fkeyu(v.z), u3 = fkeyu(v.w);
      if ((u0 & pmask) == pref)
        atomicAdd(&hist[((u0 >> shift) & 255) * 16 + rep], 1u);
      if ((u1 & pmask) == pref)
        atomicAdd(&hist[((u1 >> shift) & 255) * 16 + rep], 1u);
      if ((u2 & pmask) == pref)
        atomicAdd(&hist[((u2 >> shift) & 255) * 16 + rep], 1u);
      if ((u3 & pmask) == pref)
        atomicAdd(&hist[((u3 >> shift) & 255) * 16 + rep], 1u);
    }
    __syncthreads();
    if (tid < 256) {
      unsigned s = 0;
#pragma unroll
      for (int r2 = 0; r2 < 16; r2++) s += hist[tid * 16 + r2];
      s_hsum[tid] = s;
    }
    __syncthreads();
    if (tid == 0) {
      unsigned cum = 0;
      for (int d = 255; d >= 0; d--) {
        unsigned c = s_hsum[d];
        if (cum + c >= krem) {
          s_comm[0] = krem - cum; s_comm[1] = c; s_comm[2] = (unsigned)d;
          break;
        }
        cum += c;
      }
    }
    __syncthreads();
    krem = s_comm[0]; cntT = s_comm[1];
    pref |= s_comm[2] << shift;
    pmask |= 0xFFu << shift;
    __syncthreads();
  }
  const unsigned T = pref, r = krem;
  unsigned m = (unsigned)N;
  if (r < cntT) {  // boundary ties: smallest r indices among {u == T}
    unsigned lo = 0, hi = (unsigned)N;
    while (lo < hi) {
      unsigned mid = (lo + hi) >> 1;
      if (tid == 0) s_comm[3] = 0;
      __syncthreads();
      for (unsigned i = tid; i < mid; i += 1024)
        if (fkey(src[i]) == T) atomicAdd(&s_comm[3], 1u);
      __syncthreads();
      unsigned c = s_comm[3];
      __syncthreads();
      if (c >= r) hi = mid; else lo = mid + 1;
    }
    m = lo;
  }
  if (tid == 0) s_comm[3] = 0;
  __syncthreads();
  for (int i = tid; i < N4; i += 1024) {
    uint4 v = src4[i];
#pragma unroll
    for (int j = 0; j < 4; j++) {
      unsigned bu = (j == 0) ? v.x : (j == 1) ? v.y : (j == 2) ? v.z : v.w;
      unsigned u = fkeyu(bu);
      unsigned idx = (unsigned)(i * 4 + j);
      if (u > T || (u == T && idx < m)) {
        unsigned p = atomicAdd(&s_comm[3], 1u);
        if (p < 1024)
          keys[p] = ((unsigned long long)u << 32) | (unsigned)(~idx);
      }
    }
  }
  __syncthreads();
  if (tid >= k) keys[tid] = 0ull;  // pad; sorts to the end
  __syncthreads();
  // bitonic sort, descending
  for (unsigned k2 = 2; k2 <= 1024; k2 <<= 1) {
    for (unsigned j = k2 >> 1; j > 0; j >>= 1) {
      unsigned i = tid, ixj = i ^ j;
      if (ixj > i) {
        unsigned long long a = keys[i], b = keys[ixj];
        bool sw = ((i & k2) == 0) ? (a < b) : (a > b);
        if (sw) { keys[i] = b; keys[ixj] = a; }
      }
      __syncthreads();
    }
  }
  if (tid < k) {
    unsigned long long key = keys[tid];
    unsigned u = (unsigned)(key >> 32);
    unsigned idx = ~((unsigned)key);
    float sc = funkey(u);
    float4 b = bsrc[idx];
    if (FINAL) {
      float* o = finalOut + ((size_t)img * 1000 + tid) * 5;
      o[0] = b.x; o[1] = b.y; o[2] = b.z; o[3] = b.w; o[4] = sc;
    } else {
      scoresOut[(size_t)img * ATOT_PER_IMG + c_AOFF[lvl] + tid] = sc;
      boxesOut[(size_t)img * ATOT_PER_IMG + c_AOFF[lvl] + tid] = b;
    }
  }
}

// ------------------------------ NMS ----------------------------------------
__global__ __launch_bounds__(256) void nms_matrix(
    const float4* __restrict__ allb, unsigned long long* __restrict__ supp) {
  int lvl = blockIdx.x, img = blockIdx.y, rb = blockIdx.z;
  int k = c_KLVL[lvl];
  int task = img * 5 + lvl;
  const float4* src = allb + (size_t)img * ATOT_PER_IMG + c_AOFF[lvl];
  __shared__ float4 bb[1000];
  __shared__ float ar[1000];
  for (int j = threadIdx.x; j < k; j += 256) {
    float4 b = src[j];
    bb[j] = b;
    ar[j] = __fmul_rn(__fsub_rn(b.z, b.x), __fsub_rn(b.w, b.y));
  }
  __syncthreads();
  int i = rb * 256 + threadIdx.x;
  if (i < k) {
    float4 bi = bb[i];
    float ai = ar[i];
    unsigned long long* row = supp + ((size_t)task * 1024 + i) * 16;
    int jw0 = i >> 6;
    for (int jw = 0; jw < jw0; jw++) row[jw] = 0ull;
    for (int jw = jw0; jw < 16; jw++) {
      unsigned long long bits = 0;
      int jbase = jw * 64;
      for (int jj = 0; jj < 64; jj++) {
        int j = jbase + jj;
        if (j > i && j < k) {
          float4 bj = bb[j];
          float ltx = fmaxf(bi.x, bj.x), lty = fmaxf(bi.y, bj.y);
          float rbx = fminf(bi.z, bj.z), rby = fminf(bi.w, bj.w);
          float wx = fmaxf(__fsub_rn(rbx, ltx), 0.f);
          float wy = fmaxf(__fsub_rn(rby, lty), 0.f);
          float inter = __fmul_rn(wx, wy);
          float den = __fadd_rn(__fsub_rn(__fadd_rn(ai, ar[j]), inter), 1e-9f);
          if (__fdiv_rn(inter, den) > 0.7f) bits |= 1ull << jj;
        }
      }
      row[jw] = bits;
    }
  }
}

__global__ __launch_bounds__(64) void nms_scan(
    const float* __restrict__ topS, const unsigned long long* __restrict__ supp,
    float* __restrict__ fscore) {
  int lvl = blockIdx.x, img = blockIdx.y;
  int k = c_KLVL[lvl];
  int task = img * 5 + lvl;
  int lane = threadIdx.x;
  const unsigned long long* base = supp + (size_t)task * 1024 * 16;
  unsigned long long rem = 0, keep = 0;  // lane l<16 holds 64-bit word l
  for (int b0 = 0; b0 < k; b0 += 16) {
    unsigned long long buf[16];
#pragma unroll
    for (int t = 0; t < 16; t++) {
      int i = b0 + t;
      buf[t] = (lane < 16 && i < k) ? base[(size_t)i * 16 + lane] : 0ull;
    }
#pragma unroll
    for (int t = 0; t < 16; t++) {
      int i = b0 + t;
      if (i >= k) break;
      int wi = i >> 6, bi = i & 63;
      unsigned long long rw = __shfl(rem, wi);
      if (!((rw >> bi) & 1ull)) {  // i survives: suppress its row
        rem |= buf[t];
        if (lane == wi) keep |= (1ull << bi);
      }
    }
  }
  const float* ts = topS + (size_t)img * ATOT_PER_IMG + c_AOFF[lvl];
  float* fs = fscore + (size_t)img * ATOT_PER_IMG + c_AOFF[lvl];
  for (int i = lane; i < k; i += 64) {
    int wi = i >> 6;
    unsigned long long kw = __shfl(keep, wi);
    fs[i] = ((kw >> (i & 63)) & 1ull) ? ts[i] : -1e9f;
  }
}

// ------------------------------ host ---------------------------------------
static Anch mkAnch(double size) {
  Anch a;
  const double R[3] = {0.5, 1.0, 2.0};
  for (int i = 0; i < 3; i++) {
    double w = size * sqrt(1.0 / R[i]);
    double h = size * sqrt(R[i]);
    a.cx1[i] = (float)(-w / 2.0);
    a.cy1[i] = (float)(-h / 2.0);
  }
  return a;
}

extern "C" void kernel_launch(void* const* d_in, const int* in_sizes, int n_in,
                              void* d_out, int out_size, void* d_ws,
                              size_t ws_size, hipStream_t stream) {
  (void)in_sizes; (void)n_in; (void)out_size; (void)ws_size;
  const float* f0 = (const float*)d_in[0];
  const float* f1 = (const float*)d_in[1];
  const float* f2 = (const float*)d_in[2];
  const float* f3 = (const float*)d_in[3];
  const float* f4 = (const float*)d_in[4];
  const float* conv_w = (const float*)d_in[5];
  const float* conv_b = (const float*)d_in[6];
  const float* cls_w  = (const float*)d_in[7];
  const float* cls_b  = (const float*)d_in[8];
  const float* bbox_w = (const float*)d_in[9];
  const float* bbox_b = (const float*)d_in[10];
  float* out = (float*)d_out;

  // workspace layout (floats), all 16B-aligned; total ~14.4 MB
  float* wsf = (float*)d_ws;
  float* Wt     = wsf;                      // 589824
  float* scores = Wt + 589824;              // 2*261888
  float* boxes  = scores + 2 * NTOT_PER_IMG;       // 2*261888*4
  float* topS   = boxes + (size_t)2 * NTOT_PER_IMG * 4;  // 2*4768
  float* allb   = topS + 2 * ATOT_PER_IMG;         // 2*4768*4
  float* fscore = allb + (size_t)2 * ATOT_PER_IMG * 4;   // 2*4768
  unsigned long long* supp =
      (unsigned long long*)(fscore + 2 * ATOT_PER_IMG);  // 10*1024*16 u64

  wtrans<<<dim3(144, 16), 256, 0, stream>>>(conv_w, Wt);

  ConvCfg cfg;
  const double SZ[5] = {32, 64, 128, 256, 512};
  for (int l = 0; l < 5; l++) cfg.an[l] = mkAnch(SZ[l]);

  conv_gemm<<<2728, 256, 0, stream>>>(f0, f1, f2, f3, f4, Wt, conv_b, cls_w,
                                      cls_b, bbox_w, bbox_b, scores,
                                      (float4*)boxes, cfg);

  topk_kernel<false><<<dim3(5, 2), 1024, 0, stream>>>(
      scores, (const float4*)boxes, topS, (float4*)allb, nullptr);
  nms_matrix<<<dim3(5, 2, 4), 256, 0, stream>>>((const float4*)allb, supp);
  nms_scan<<<dim3(5, 2), 64, 0, stream>>>(topS, supp, fscore);
  topk_kernel<true><<<2, 1024, 0, stream>>>(
      fscore, (const float4*)allb, nullptr, nullptr, out);
}